// Round 2
// baseline (219.218 us; speedup 1.0000x reference)
//
#include <hip/hip_runtime.h>

// NonImagingRod: per-ray damped-Newton (LM) root find on f(t) = A t^2 + B t + C.
// Inner loop runs on the (f, f') pair directly (quadratic Taylor update is
// exact), in packed-fp32 (float2 -> v_pk_fma_f32) with 8 rays/thread.
// loss = loss_in + mean(f_final^2); finalize fused via ticket counter.

#define LM_ITERS 31
constexpr float DAMPING   = 0.5f;
constexpr float MAX_DELTA = 1000.0f;

typedef float v2f __attribute__((ext_vector_type(2)));

static __device__ __forceinline__ v2f vfma(v2f a, v2f b, v2f c) {
    return __builtin_elementwise_fma(a, b, c);
}

__global__ __launch_bounds__(256) void rod_kernel(
    const float* __restrict__ P, const float* __restrict__ V,
    const float* __restrict__ Rm, const float* __restrict__ Tv,
    const float* __restrict__ c_ptr, const float* __restrict__ loss_in,
    double* __restrict__ ws, float* __restrict__ out,
    int n, double inv_n)
{
    const float c  = c_ptr[0];
    const float r00 = Rm[0], r01 = Rm[1], r02 = Rm[2];
    const float r10 = Rm[3], r11 = Rm[4], r12 = Rm[5];
    const float r20 = Rm[6], r21 = Rm[7], r22 = Rm[8];
    const float t0 = Tv[0], t1 = Tv[1], t2 = Tv[2];

    const int tid  = blockIdx.x * blockDim.x + threadIdx.x;
    const int base = tid * 8;                 // 8 rays per thread

    double acc = 0.0;
    if (base + 8 <= n) {
        // 8 rays: 6 float4 loads from each of P and V.
        union { float4 q[6]; float s[24]; } up, uv;
        const float4* P4 = (const float4*)P;
        const float4* V4 = (const float4*)V;
        #pragma unroll
        for (int i = 0; i < 6; ++i) { up.q[i] = P4[tid * 6 + i]; uv.q[i] = V4[tid * 6 + i]; }

        // Per-pair state: negated A, negated 2A, f (=C at t=0), fp (=B at t=0).
        v2f nA[4], nA2[4], f[4], fp[4];
        #pragma unroll
        for (int r = 0; r < 8; ++r) {
            const float qx = up.s[3 * r + 0] - t0;
            const float qy = up.s[3 * r + 1] - t1;
            const float qz = up.s[3 * r + 2] - t2;
            const float vx = uv.s[3 * r + 0], vy = uv.s[3 * r + 1], vz = uv.s[3 * r + 2];
            const float plx = qx * r00 + qy * r10 + qz * r20;
            const float ply = qx * r01 + qy * r11 + qz * r21;
            const float plz = qx * r02 + qy * r12 + qz * r22;
            const float vlx = vx * r00 + vy * r10 + vz * r20;
            const float vly = vx * r01 + vy * r11 + vz * r21;
            const float vlz = vx * r02 + vy * r12 + vz * r22;
            const float A  = -c * (vly * vly + vlz * vlz);
            const float B  = vlx - 2.0f * c * (ply * vly + plz * vlz);
            const float C  = plx - c * (ply * ply + plz * plz);
            const int j = r >> 1, k = r & 1;
            nA[j][k]  = -A;
            nA2[j][k] = -2.0f * A;
            f[j][k]   = C;      // f(0)
            fp[j][k]  = B;      // f'(0)
        }

        const v2f vdamp = {DAMPING, DAMPING};
        const v2f vlo   = {-MAX_DELTA, -MAX_DELTA};
        const v2f vhi   = { MAX_DELTA,  MAX_DELTA};

        #pragma unroll 1
        for (int it = 0; it < LM_ITERS; ++it) {
            #pragma unroll
            for (int j = 0; j < 4; ++j) {
                const v2f den = vfma(fp[j], fp[j], vdamp);
                v2f rcp;
                rcp.x = __builtin_amdgcn_rcpf(den.x);   // ~1 ulp; LM self-corrects
                rcp.y = __builtin_amdgcn_rcpf(den.y);
                const v2f num = f[j] * fp[j];
                v2f d = num * rcp;
                d = __builtin_elementwise_min(__builtin_elementwise_max(d, vlo), vhi);
                // f(t-d) = f - d*(fp - A*d);  fp(t-d) = fp - 2A*d
                const v2f tmp = vfma(nA[j], d, fp[j]);
                f[j]  = vfma(-d, tmp, f[j]);
                fp[j] = vfma(nA2[j], d, fp[j]);
            }
        }

        #pragma unroll
        for (int j = 0; j < 4; ++j) {
            acc += (double)f[j].x * (double)f[j].x;
            acc += (double)f[j].y * (double)f[j].y;
        }
    } else if (base < n) {
        // Scalar tail (not hit for n % 8 == 0, kept for generality).
        for (int r = base; r < n; ++r) {
            const float qx = P[3 * r + 0] - t0, qy = P[3 * r + 1] - t1, qz = P[3 * r + 2] - t2;
            const float vx = V[3 * r + 0], vy = V[3 * r + 1], vz = V[3 * r + 2];
            const float ply = qx * r01 + qy * r11 + qz * r21;
            const float plz = qx * r02 + qy * r12 + qz * r22;
            const float plx = qx * r00 + qy * r10 + qz * r20;
            const float vlx = vx * r00 + vy * r10 + vz * r20;
            const float vly = vx * r01 + vy * r11 + vz * r21;
            const float vlz = vx * r02 + vy * r12 + vz * r22;
            const float A = -c * (vly * vly + vlz * vlz);
            float fpv = vlx - 2.0f * c * (ply * vly + plz * vlz);
            float fv  = plx - c * (ply * ply + plz * plz);
            for (int it = 0; it < LM_ITERS; ++it) {
                const float den = fmaf(fpv, fpv, DAMPING);
                float d = fv * fpv * __builtin_amdgcn_rcpf(den);
                d = fminf(fmaxf(d, -MAX_DELTA), MAX_DELTA);
                const float tmp = fmaf(-A, d, fpv);
                fv  = fmaf(-d, tmp, fv);
                fpv = fmaf(-2.0f * A, d, fpv);
            }
            acc += (double)fv * (double)fv;
        }
    }

    // wave(64) shuffle reduce -> LDS across 4 waves -> one f64 atomic per block
    for (int off = 32; off > 0; off >>= 1)
        acc += __shfl_down(acc, off, 64);
    __shared__ double sacc[4];
    const int lane = threadIdx.x & 63, wave = threadIdx.x >> 6;
    if (lane == 0) sacc[wave] = acc;
    __syncthreads();
    if (threadIdx.x == 0) {
        double* ws_acc = ws;
        unsigned int* ws_cnt = (unsigned int*)(ws + 1);
        atomicAdd(ws_acc, sacc[0] + sacc[1] + sacc[2] + sacc[3]);
        __threadfence();
        const unsigned int old = atomicAdd(ws_cnt, 1u);
        if (old == gridDim.x - 1) {
            const double total = atomicAdd(ws_acc, 0.0);   // fresh device-scope read
            out[0] = (float)(total * inv_n + (double)loss_in[0]);
        }
    }
}

extern "C" void kernel_launch(void* const* d_in, const int* in_sizes, int n_in,
                              void* d_out, int out_size, void* d_ws, size_t ws_size,
                              hipStream_t stream) {
    const float* P       = (const float*)d_in[0];
    const float* V       = (const float*)d_in[1];
    const float* R       = (const float*)d_in[2];
    const float* T       = (const float*)d_in[3];
    const float* c       = (const float*)d_in[4];
    const float* loss_in = (const float*)d_in[5];

    const int n = in_sizes[0] / 3;            // number of rays

    // ws[0] = f64 accumulator, ws[8..11] = ticket counter — zero both.
    hipMemsetAsync(d_ws, 0, 16, stream);

    const int threads = (n + 7) / 8;          // 8 rays per thread
    const int block   = 256;
    const int grid    = (threads + block - 1) / block;
    rod_kernel<<<grid, block, 0, stream>>>(P, V, R, T, c, loss_in,
                                           (double*)d_ws, (float*)d_out,
                                           n, 1.0 / (double)n);
}